// Round 1
// baseline (1050.440 us; speedup 1.0000x reference)
//
#include <hip/hip_runtime.h>
#include <stdint.h>

#define DEV __device__ __forceinline__

typedef short bf16x8 __attribute__((ext_vector_type(8)));
typedef float f32x4 __attribute__((ext_vector_type(4)));

constexpr int CB = 8, CN = 1024, CS = 1024, CC = 768, CH = 12, CD = 64;

DEV unsigned short f32_to_bf16(float f) {
    unsigned int u = __builtin_bit_cast(unsigned int, f);
    u += 0x7fffu + ((u >> 16) & 1u);
    return (unsigned short)(u >> 16);
}
DEV float bf16_to_f32(unsigned short h) {
    return __builtin_bit_cast(float, (unsigned int)h << 16);
}

DEV uint4 load8_bf16(const float* __restrict__ src) {
    const float4 a = reinterpret_cast<const float4*>(src)[0];
    const float4 b = reinterpret_cast<const float4*>(src)[1];
    union { unsigned short s[8]; uint4 v; } u;
    u.s[0] = f32_to_bf16(a.x); u.s[1] = f32_to_bf16(a.y);
    u.s[2] = f32_to_bf16(a.z); u.s[3] = f32_to_bf16(a.w);
    u.s[4] = f32_to_bf16(b.x); u.s[5] = f32_to_bf16(b.y);
    u.s[6] = f32_to_bf16(b.z); u.s[7] = f32_to_bf16(b.w);
    return u.v;
}
DEV uint4 load8_bf16(const unsigned short* __restrict__ src) {
    return *reinterpret_cast<const uint4*>(src);
}

// C[z; m,n] = scale * sum_k A[z; m,k] * B[z; n,k]  (+ bias[n])
// z = bb*Hb + hh ; A offset bb*sAb + hh*sAh (same for B, C)
// C element (m,n) stored at m*cSM + n*cSN. Requires M%64==0, Ndim%64==0, K%32==0.
template<typename TA, typename TB, typename TC>
__global__ __launch_bounds__(256)
void gemm_nt(const TA* __restrict__ Ag, const TB* __restrict__ Bg, TC* __restrict__ Cg,
             int M, int Ndim, int K, int lda, int ldb, int Hb,
             long sAb, long sAh, long sBb, long sBh, long sCb, long sCh,
             long cSM, long cSN, float scale, const float* __restrict__ bias)
{
    const int bb = blockIdx.z / Hb;
    const int hh = blockIdx.z % Hb;
    const TA* __restrict__ A  = Ag + bb * sAb + hh * sAh;
    const TB* __restrict__ Bp = Bg + bb * sBb + hh * sBh;
    TC* __restrict__ C = Cg + bb * sCb + hh * sCh;

    const int tileM = blockIdx.x * 64;
    const int tileN = blockIdx.y * 64;
    const int tid  = threadIdx.x;
    const int lane = tid & 63;
    const int wv   = tid >> 6;
    const int wr   = (wv >> 1) * 32;   // wave row offset in tile
    const int wc   = (wv & 1) * 32;    // wave col offset
    const int l15  = lane & 15;
    const int quad = lane >> 4;

    constexpr int LDP = 40;            // padded LDS row stride (elems) — conflict-light
    __shared__ unsigned short As[64 * LDP];
    __shared__ unsigned short Bs[64 * LDP];

    f32x4 acc[2][2] = {};

    const int ldRow = tid >> 2;        // 0..63
    const int ldCol = (tid & 3) * 8;   // 0,8,16,24

    const TA* aSrc = A  + (long)(tileM + ldRow) * lda + ldCol;
    const TB* bSrc = Bp + (long)(tileN + ldRow) * ldb + ldCol;
    uint4* aDst = reinterpret_cast<uint4*>(&As[ldRow * LDP + ldCol]);
    uint4* bDst = reinterpret_cast<uint4*>(&Bs[ldRow * LDP + ldCol]);

    for (int k0 = 0; k0 < K; k0 += 32) {
        *aDst = load8_bf16(aSrc + k0);
        *bDst = load8_bf16(bSrc + k0);
        __syncthreads();
        bf16x8 af[2], bfr[2];
        #pragma unroll
        for (int i = 0; i < 2; ++i)
            af[i] = *reinterpret_cast<const bf16x8*>(&As[(wr + i*16 + l15) * LDP + quad*8]);
        #pragma unroll
        for (int j = 0; j < 2; ++j)
            bfr[j] = *reinterpret_cast<const bf16x8*>(&Bs[(wc + j*16 + l15) * LDP + quad*8]);
        #pragma unroll
        for (int i = 0; i < 2; ++i)
            #pragma unroll
            for (int j = 0; j < 2; ++j)
                acc[i][j] = __builtin_amdgcn_mfma_f32_16x16x32_bf16(af[i], bfr[j], acc[i][j], 0, 0, 0);
        __syncthreads();
    }

    // C/D layout (m89-verified): col = lane&15, row = (lane>>4)*4 + reg
    #pragma unroll
    for (int i = 0; i < 2; ++i) {
        #pragma unroll
        for (int j = 0; j < 2; ++j) {
            const int col = tileN + wc + j*16 + l15;
            const float bv = bias ? bias[col] : 0.0f;
            #pragma unroll
            for (int r = 0; r < 4; ++r) {
                const int row = tileM + wr + i*16 + quad*4 + r;
                const float v = acc[i][j][r] * scale + bv;
                const long idx = (long)row * cSM + (long)col * cSN;
                if constexpr (sizeof(TC) == 2) C[idx] = f32_to_bf16(v);
                else                           C[idx] = v;
            }
        }
    }
}

// One wave per row of S=1024. Reads pre-scaled scores (bf16) + attn_weight (f32),
// writes log_attn (f32) and probs (bf16, in-place over scores).
__global__ __launch_bounds__(256)
void softmax_k(const unsigned short* __restrict__ scores,
               const float* __restrict__ aw,
               float* __restrict__ log_attn,
               unsigned short* __restrict__ probs)
{
    const int lane = threadIdx.x & 63;
    const int wv   = threadIdx.x >> 6;
    const long row  = (long)blockIdx.x * 4 + wv;
    const long base = row * CS;

    float sc[16], t[16];
    #pragma unroll
    for (int j = 0; j < 16; ++j) {
        const int col = lane + j * 64;
        sc[j] = bf16_to_f32(scores[base + col]);
        t[j]  = aw[base + col] + sc[j];
    }
    float m1 = -3.4e38f, m2 = -3.4e38f;
    #pragma unroll
    for (int j = 0; j < 16; ++j) { m1 = fmaxf(m1, sc[j]); m2 = fmaxf(m2, t[j]); }
    #pragma unroll
    for (int off = 1; off < 64; off <<= 1) {
        m1 = fmaxf(m1, __shfl_xor(m1, off));
        m2 = fmaxf(m2, __shfl_xor(m2, off));
    }
    float l1 = 0.f, l2 = 0.f;
    #pragma unroll
    for (int j = 0; j < 16; ++j) { l1 += __expf(sc[j] - m1); l2 += __expf(t[j] - m2); }
    #pragma unroll
    for (int off = 1; off < 64; off <<= 1) {
        l1 += __shfl_xor(l1, off);
        l2 += __shfl_xor(l2, off);
    }
    const float lse1 = m1 + __logf(l1);
    const float inv2 = 1.0f / l2;
    #pragma unroll
    for (int j = 0; j < 16; ++j) {
        const int col = lane + j * 64;
        log_attn[base + col] = t[j] - lse1;
        probs[base + col]    = f32_to_bf16(__expf(t[j] - m2) * inv2);
    }
}

extern "C" void kernel_launch(void* const* d_in, const int* in_sizes, int n_in,
                              void* d_out, int out_size, void* d_ws, size_t ws_size,
                              hipStream_t stream)
{
    const float* query = (const float*)d_in[0];
    const float* key_  = (const float*)d_in[1];
    const float* value = (const float*)d_in[2];
    const float* aw    = (const float*)d_in[3];
    const float* Wq    = (const float*)d_in[4];
    const float* Wk    = (const float*)d_in[5];
    const float* Wv    = (const float*)d_in[6];
    const float* Wo    = (const float*)d_in[7];
    const float* bo    = (const float*)d_in[8];

    float* out      = (float*)d_out;                       // [B,N,C]
    float* log_attn = out + (long)CB * CN * CC;            // [B,H,N,S]

    // workspace layout (bf16 elems): total 251,658,240 bytes
    unsigned short* qproj = (unsigned short*)d_ws;                    // [B*N, C]
    unsigned short* kproj = qproj + (long)CB * CN * CC;               // [B*S, C]
    unsigned short* vT    = kproj + (long)CB * CS * CC;               // [B,H,D,S]
    unsigned short* sp    = vT    + (long)CB * CS * CC;               // scores→probs [B,H,N,S]
    unsigned short* aout  = sp    + (long)CB * CH * CN * CS;          // [B,N,H*D]

    const dim3 blk(256);

    // Q = query @ Wq^T  -> bf16 [8192,768]
    gemm_nt<float, float, unsigned short><<<dim3(128, 12, 1), blk, 0, stream>>>(
        query, Wq, qproj, CB*CN, CC, CC, CC, CC, 1,
        0, 0, 0, 0, 0, 0, (long)CC, 1, 1.0f, nullptr);
    // K = key @ Wk^T
    gemm_nt<float, float, unsigned short><<<dim3(128, 12, 1), blk, 0, stream>>>(
        key_, Wk, kproj, CB*CS, CC, CC, CC, CC, 1,
        0, 0, 0, 0, 0, 0, (long)CC, 1, 1.0f, nullptr);
    // V = value @ Wv^T, written transposed per batch: vT[b, h, d, s]
    gemm_nt<float, float, unsigned short><<<dim3(16, 12, 8), blk, 0, stream>>>(
        value, Wv, vT, CS, CC, CC, CC, CC, 1,
        (long)CS*CC, 0, 0, 0, (long)CH*CD*CS, 0, 1, (long)CS, 1.0f, nullptr);
    // scores[b,h] = SCALE * q_head @ k_head^T   (K=64)
    gemm_nt<unsigned short, unsigned short, unsigned short><<<dim3(16, 16, CB*CH), blk, 0, stream>>>(
        qproj, kproj, sp, CN, CS, CD, CC, CC, CH,
        (long)CN*CC, (long)CD, (long)CS*CC, (long)CD,
        (long)CH*CN*CS, (long)CN*CS, (long)CS, 1, 0.125f, nullptr);
    // dual softmax: log_attn out + probs (in-place)
    softmax_k<<<dim3(CB*CH*CN/4), blk, 0, stream>>>(sp, aw, log_attn, sp);
    // head_out[b,h] = probs @ v_head ; stored as [B,N,H*D] bf16
    gemm_nt<unsigned short, unsigned short, unsigned short><<<dim3(16, 1, CB*CH), blk, 0, stream>>>(
        sp, vT, aout, CN, CD, CS, CS, CS, CH,
        (long)CH*CN*CS, (long)CN*CS, (long)CH*CD*CS, (long)CD*CS,
        (long)CN*CC, (long)CD, (long)CC, 1, 1.0f, nullptr);
    // out = head_out @ Wo^T + bo  (fp32 out)
    gemm_nt<unsigned short, float, float><<<dim3(128, 12, 1), blk, 0, stream>>>(
        aout, Wo, out, CB*CN, CC, CC, CC, CC, 1,
        0, 0, 0, 0, 0, 0, (long)CC, 1, 1.0f, bo);
}